// Round 6
// baseline (227.210 us; speedup 1.0000x reference)
//
#include <hip/hip_runtime.h>

// out = softmax(q @ keys^T) @ keys, fused flash-style, round 6.
// vs r5: 32 q-rows/wave (LDS A/B-frags amortized over 2 q-groups) while
// keeping 8 waves/CU by SPLITTING the 64 K-tiles across wave pairs
// (s=0: tiles 0..31, s=1: 32..63) with an end-of-kernel flash-combine
// through LDS. Score-read swizzle fixed to 2-way (xkey = qr&7). Single-
// buffered per-split tiles, 2 barriers/tile, grid 512 x 256, 2 blocks/CU.

typedef _Float16 f16;
typedef f16 f16x8 __attribute__((ext_vector_type(8)));
typedef float f32x4 __attribute__((ext_vector_type(4)));

#define MF32(a, b, c) __builtin_amdgcn_mfma_f32_16x16x32_f16(a, b, c, 0, 0, 0)

__device__ __forceinline__ void gl_lds16(const f16* g, f16* l) {
  __builtin_amdgcn_global_load_lds(
      (const __attribute__((address_space(1))) void*)g,
      (__attribute__((address_space(3))) void*)l, 16, 0, 0);
}

// ---- pre-kernel: swizzled per-tile images (grid 256 x 256) ----
__global__ void prep_kernel(const float* __restrict__ keys, f16* __restrict__ ws) {
  int i = blockIdx.x * 256 + threadIdx.x;  // 0..65535
  int t = i >> 10;
  {  // Kh image: key kk, chunk c; slot = c ^ ((kk&3)|(((kk>>3)&1)<<2))
    int kk = (i >> 5) & 31, c = i & 31;
    const float* src = keys + (((t << 5) + kk) << 8) + (c << 3);
    f16x8 v;
    #pragma unroll
    for (int e = 0; e < 8; ++e) v[e] = (f16)src[e];
    int xk = (kk & 3) | (((kk >> 3) & 1) << 2);
    *(f16x8*)&ws[t * 8192 + kk * 256 + ((c ^ xk) << 3)] = v;
  }
  {  // KT image (unchanged): dim d, key-group g
    int d = (i >> 2) & 255, g = i & 3;
    const float* src = keys + (((t << 5) + (g << 3)) << 8) + d;
    f16x8 v;
    #pragma unroll
    for (int j = 0; j < 8; ++j) v[j] = (f16)src[j << 8];
    *(f16x8*)&ws[524288 + t * 8192 + (d >> 1) * 64 +
                 (((((d & 1) << 2) | g) ^ ((d >> 1) & 7)) << 3)] = v;
  }
}

#define STORE_HALF(DTB)                                                     \
  {                                                                         \
    _Pragma("unroll") for (int j = 0; j < 16; ++j) {                        \
      const int dt = (DTB) + (j >> 1);                                      \
      const int grp = j & 1;                                                \
      f32x4 pv = *(const f32x4*)(rdp + (((j + lane) & 15) << 4));           \
      f32x4 ow = grp ? O1[dt] : O0[dt];                                     \
      float4 w4;                                                            \
      w4.x = (ow[0] * A_[grp][0] + pv[0] * B_[grp][0]) * N_[grp][0];        \
      w4.y = (ow[1] * A_[grp][1] + pv[1] * B_[grp][1]) * N_[grp][1];        \
      w4.z = (ow[2] * A_[grp][2] + pv[2] * B_[grp][2]) * N_[grp][2];        \
      w4.w = (ow[3] * A_[grp][3] + pv[3] * B_[grp][3]) * N_[grp][3];        \
      int c = dt * 16 + qr;                                                 \
      *(float4*)(ob + ((size_t)c << 12) + grp * 16) = w4;                   \
    }                                                                       \
  }

__global__ __launch_bounds__(256, 2)
void mtr_kernel(const f16* __restrict__ ws,
                const float* __restrict__ query,
                float* __restrict__ out) {
  // [0,16K): KB0  [16K,32K)... f16 idx: KB0=0, KT0=8192, KB1=16384, KT1=24576
  __shared__ f16 SH[32768];            // 64 KB tile buffers / combine region
  __shared__ float ML[2][2][64][4];    // 4 KB: per-pair, per-split {m0,l0,m1,l1}

  const int tid  = threadIdx.x;
  const int lane = tid & 63;
  const int wave = tid >> 6;   // 0..3
  const int p    = wave >> 1;  // q-pair: rows [p*32, p*32+32)
  const int s    = wave & 1;   // tile-split: tiles [s*32, s*32+32)
  const int g    = lane >> 4;  // 0..3
  const int qr   = lane & 15;

  const int nbase  = blockIdx.x * 64;
  const int b      = nbase >> 12;
  const int hwbase = nbase & 4095;

  // ---- q fragments, 2 groups of 16 rows, hi/lo fp16 split (q exact).
  f16x8 qh0[8], ql0[8], qh1[8], ql1[8];
  #pragma unroll
  for (int grp = 0; grp < 2; ++grp) {
    const float* qb = query + ((size_t)b << 20) + hwbase + p * 32 + grp * 16 + qr;
    #pragma unroll
    for (int dt = 0; dt < 8; ++dt)
      #pragma unroll
      for (int j = 0; j < 8; ++j) {
        int c = dt * 32 + g * 8 + j;
        float v = qb[(size_t)c << 12];
        f16 h = (f16)v;
        if (grp == 0) { qh0[dt][j] = h; ql0[dt][j] = (f16)(v - (float)h); }
        else          { qh1[dt][j] = h; ql1[dt][j] = (f16)(v - (float)h); }
      }
  }

  f32x4 O0[16], O1[16];
  #pragma unroll
  for (int i = 0; i < 16; ++i) {
    O0[i] = (f32x4){0.f, 0.f, 0.f, 0.f};
    O1[i] = (f32x4){0.f, 0.f, 0.f, 0.f};
  }
  float m0 = -INFINITY, l0 = 0.f, m1 = -INFINITY, l1 = 0.f;

  // score A-rows: key-permuted phys key = 8*(qr>>2) + 4*kt + (qr&3)
  const int rb0 = (((qr >> 2) << 3) + (qr & 3)) << 8;
  const int rb1 = rb0 + 1024;
  const int xs  = qr & 7;  // matches prep xkey for both rb0/rb1 rows
  const int rbT = ((qr >> 1) << 6) + (((((qr & 1) << 2) | g) ^ ((qr >> 1) & 7)) << 3);

  // staging: wave (p,s) stages KB_s (p==0) or KT_s (p==1), 16 x 1KB
  const f16* wsbase = ws + (p ? 524288 : 0) + lane * 8;
  f16* sdst = &SH[s * 16384 + (p ? 8192 : 0)];

  {  // prologue: stage tile s*32
    const f16* sp = wsbase + (s * 32) * 8192;
    #pragma unroll
    for (int i = 0; i < 16; ++i) gl_lds16(sp + i * 512, sdst + i * 512);
  }
  __syncthreads();

  const f16* KBc = &SH[s * 16384];
  const f16* KTc = KBc + 8192;

  for (int tl = 0; tl < 32; ++tl) {
    // ---- score: both q-groups share the A-frags
    f32x4 s00 = (f32x4){0.f,0.f,0.f,0.f}, s10 = (f32x4){0.f,0.f,0.f,0.f};
    f32x4 s01 = (f32x4){0.f,0.f,0.f,0.f}, s11 = (f32x4){0.f,0.f,0.f,0.f};
    #pragma unroll
    for (int dt = 0; dt < 8; ++dt) {
      int c = (dt << 2) + g;
      f16x8 a0 = *(const f16x8*)&KBc[rb0 + ((c ^ xs) << 3)];
      f16x8 a1 = *(const f16x8*)&KBc[rb1 + ((c ^ xs) << 3)];
      s00 = MF32(a0, qh0[dt], s00); s00 = MF32(a0, ql0[dt], s00);
      s10 = MF32(a1, qh0[dt], s10); s10 = MF32(a1, ql0[dt], s10);
      s01 = MF32(a0, qh1[dt], s01); s01 = MF32(a0, ql1[dt], s01);
      s11 = MF32(a1, qh1[dt], s11); s11 = MF32(a1, ql1[dt], s11);
    }

    // ---- online softmax per group; build PV A-frags
    f16x8 pa0, pa1;
    #pragma unroll
    for (int grp = 0; grp < 2; ++grp) {
      f32x4& sa = grp ? s01 : s00;
      f32x4& sb = grp ? s11 : s10;
      float& mr = grp ? m1 : m0;
      float& lr = grp ? l1 : l0;
      float tmax = fmaxf(fmaxf(fmaxf(sa[0], sa[1]), fmaxf(sa[2], sa[3])),
                         fmaxf(fmaxf(sb[0], sb[1]), fmaxf(sb[2], sb[3])));
      tmax = fmaxf(tmax, __shfl_xor(tmax, 16));
      tmax = fmaxf(tmax, __shfl_xor(tmax, 32));
      if (__any(tmax > mr + 8.f)) {  // defer-max (T13)
        float m_new = fmaxf(mr, tmax);
        float sc = __expf(mr - m_new);
        lr *= sc;
        mr = m_new;
        float osc0 = __shfl(sc, g * 4 + 0);
        float osc1 = __shfl(sc, g * 4 + 1);
        float osc2 = __shfl(sc, g * 4 + 2);
        float osc3 = __shfl(sc, g * 4 + 3);
        f32x4* O = grp ? O1 : O0;
        #pragma unroll
        for (int dtile = 0; dtile < 16; ++dtile) {
          O[dtile][0] *= osc0; O[dtile][1] *= osc1;
          O[dtile][2] *= osc2; O[dtile][3] *= osc3;
        }
      }
      float ts = 0.f;
      f16x8& pa = grp ? pa1 : pa0;
      #pragma unroll
      for (int i = 0; i < 4; ++i) {
        float e0 = __expf(sa[i] - mr);
        float e1 = __expf(sb[i] - mr);
        ts += e0 + e1;
        pa[i] = (f16)e0;
        pa[4 + i] = (f16)e1;
      }
      ts += __shfl_xor(ts, 16);
      ts += __shfl_xor(ts, 32);
      lr += ts;
    }

    // ---- PV: B-frags shared by both groups
    #pragma unroll
    for (int dtile = 0; dtile < 16; ++dtile) {
      f16x8 vb = *(const f16x8*)&KTc[dtile * 512 + rbT];
      O0[dtile] = MF32(pa0, vb, O0[dtile]);
      O1[dtile] = MF32(pa1, vb, O1[dtile]);
    }

    __syncthreads();  // all waves done reading their split's buffers
    if (tl + 1 < 32) {
      const f16* sp = wsbase + (s * 32 + tl + 1) * 8192;
      #pragma unroll
      for (int i = 0; i < 16; ++i) gl_lds16(sp + i * 512, sdst + i * 512);
    }
    __syncthreads();  // barrier drains vmcnt -> buffers ready
  }

  // ---------- flash-combine across splits (through dead tile buffers) ----------
  char* pairR = (char*)SH + p * 32768;
  {  // write the half the PARTNER will store (dtiles (1-s)*8 ..+8), rotated
    char* wrp = pairR + s * 16384 + lane * 256;
    if (s == 0) {
      #pragma unroll
      for (int j = 0; j < 16; ++j) {
        f32x4 ow = (j & 1) ? O1[8 + (j >> 1)] : O0[8 + (j >> 1)];
        *(f32x4*)(wrp + (((j + lane) & 15) << 4)) = ow;
      }
    } else {
      #pragma unroll
      for (int j = 0; j < 16; ++j) {
        f32x4 ow = (j & 1) ? O1[j >> 1] : O0[j >> 1];
        *(f32x4*)(wrp + (((j + lane) & 15) << 4)) = ow;
      }
    }
    ML[p][s][lane][0] = m0; ML[p][s][lane][1] = l0;
    ML[p][s][lane][2] = m1; ML[p][s][lane][3] = l1;
  }
  __syncthreads();

  float A_[2][4], B_[2][4], N_[2][4];
  {
    float mo0 = ML[p][s ^ 1][lane][0], lo0 = ML[p][s ^ 1][lane][1];
    float mo1 = ML[p][s ^ 1][lane][2], lo1 = ML[p][s ^ 1][lane][3];
    float ms0 = fmaxf(m0, mo0);
    float al0 = __expf(m0 - ms0), be0 = __expf(mo0 - ms0);
    float ivl0 = 1.f / (l0 * al0 + lo0 * be0);
    float ms1 = fmaxf(m1, mo1);
    float al1 = __expf(m1 - ms1), be1 = __expf(mo1 - ms1);
    float ivl1 = 1.f / (l1 * al1 + lo1 * be1);
    #pragma unroll
    for (int i = 0; i < 4; ++i) {
      A_[0][i] = __shfl(al0, g * 4 + i);
      B_[0][i] = __shfl(be0, g * 4 + i);
      N_[0][i] = __shfl(ivl0, g * 4 + i);
      A_[1][i] = __shfl(al1, g * 4 + i);
      B_[1][i] = __shfl(be1, g * 4 + i);
      N_[1][i] = __shfl(ivl1, g * 4 + i);
    }
  }
  const char* rdp = pairR + (s ^ 1) * 16384 + lane * 256;
  float* ob = out + ((size_t)b << 20) + hwbase + p * 32 + g * 4;
  if (s == 0) STORE_HALF(0) else STORE_HALF(8)
}

extern "C" void kernel_launch(void* const* d_in, const int* in_sizes, int n_in,
                              void* d_out, int out_size, void* d_ws, size_t ws_size,
                              hipStream_t stream) {
  const float* keys  = (const float*)d_in[0];
  const float* query = (const float*)d_in[1];
  float* out = (float*)d_out;
  f16* ws = (f16*)d_ws;
  hipLaunchKernelGGL(prep_kernel, dim3(256), dim3(256), 0, stream, keys, ws);
  hipLaunchKernelGGL(mtr_kernel, dim3(512), dim3(256), 0, stream, ws, query, out);
}